// Round 7
// baseline (770.579 us; speedup 1.0000x reference)
//
#include <hip/hip_runtime.h>
#include <hip/hip_bf16.h>

// ---------- types ----------
typedef __attribute__((ext_vector_type(8))) short bf16x8;  // 8 bf16 in 4 VGPRs
typedef __attribute__((ext_vector_type(4))) float f32x4;

__device__ __forceinline__ unsigned short f2bf(float f) {
  union { float f; unsigned u; } v; v.f = f;
  unsigned r = v.u + 0x7FFFu + ((v.u >> 16) & 1u);  // RNE
  return (unsigned short)(r >> 16);
}

__device__ __forceinline__ void gl_lds16(const void* g, void* l) {
  __builtin_amdgcn_global_load_lds(
      (__attribute__((address_space(1))) void*)(g),
      (__attribute__((address_space(3))) void*)(l), 16, 0, 0);
}

// ---------- f32 -> bf16 convert (vectorized) ----------
__global__ __launch_bounds__(256) void k_convert(const float* __restrict__ in,
                                                 unsigned short* __restrict__ out,
                                                 int n8) {
  int i = blockIdx.x * 256 + threadIdx.x;
  if (i >= n8) return;
  const float4* ip = (const float4*)in;
  float4 v0 = ip[2 * i], v1 = ip[2 * i + 1];
  ushort4 o0 = make_ushort4(f2bf(v0.x), f2bf(v0.y), f2bf(v0.z), f2bf(v0.w));
  ushort4 o1 = make_ushort4(f2bf(v1.x), f2bf(v1.y), f2bf(v1.z), f2bf(v1.w));
  ((ushort4*)out)[2 * i] = o0;
  ((ushort4*)out)[2 * i + 1] = o1;
}

// ---------- batched transpose: in [R][C] f32 -> out [C][R] (f32 or bf16) ----------
template <typename OutT>
__global__ __launch_bounds__(256) void k_transpose(const float* __restrict__ in,
                                                   OutT* __restrict__ out,
                                                   int R, int C,
                                                   long inStride, long outStride) {
  __shared__ float tile[64][65];
  const float* ib = in + (long)blockIdx.z * inStride;
  OutT* ob = out + (long)blockIdx.z * outStride;
  int tc = blockIdx.x * 64;
  int tr = blockIdx.y * 64;
  int t = threadIdx.x;
  int lr = t >> 4;
  int lc = (t & 15) * 4;
#pragma unroll
  for (int rr = 0; rr < 64; rr += 16) {
    float4 v = *(const float4*)&ib[(long)(tr + rr + lr) * C + tc + lc];
    tile[rr + lr][lc + 0] = v.x;
    tile[rr + lr][lc + 1] = v.y;
    tile[rr + lr][lc + 2] = v.z;
    tile[rr + lr][lc + 3] = v.w;
  }
  __syncthreads();
#pragma unroll
  for (int ii = 0; ii < 64; ii += 16) {
    int i = ii + lr;
    if constexpr (sizeof(OutT) == 2) {
      ushort4 w = make_ushort4(f2bf(tile[lc + 0][i]), f2bf(tile[lc + 1][i]),
                               f2bf(tile[lc + 2][i]), f2bf(tile[lc + 3][i]));
      *(ushort4*)&ob[(long)(tc + i) * R + tr + lc] = w;
    } else {
      float4 w = make_float4(tile[lc + 0][i], tile[lc + 1][i],
                             tile[lc + 2][i], tile[lc + 3][i]);
      *(float4*)&ob[(long)(tc + i) * R + tr + lc] = w;
    }
  }
}

// ---------- phase 1: partial column stats (online max/sumexp over 128-row chunk) ----------
__global__ __launch_bounds__(256) void k_colstats(const float* __restrict__ E,
                                                  float* __restrict__ colMp,
                                                  float* __restrict__ colSp) {
  const float* e = E + (long)blockIdx.y * 1048576L + (long)blockIdx.x * 131072L +
                   threadIdx.x * 4;
  float m0 = -3.4e38f, m1 = -3.4e38f, m2 = -3.4e38f, m3 = -3.4e38f;
  float s0 = 0.f, s1 = 0.f, s2 = 0.f, s3 = 0.f;
  for (int r = 0; r < 128; ++r) {
    float4 v = *(const float4*)(e + (long)r * 1024);
    float n0 = fmaxf(m0, v.x); s0 = s0 * __expf(m0 - n0) + __expf(v.x - n0); m0 = n0;
    float n1 = fmaxf(m1, v.y); s1 = s1 * __expf(m1 - n1) + __expf(v.y - n1); m1 = n1;
    float n2 = fmaxf(m2, v.z); s2 = s2 * __expf(m2 - n2) + __expf(v.z - n2); m2 = n2;
    float n3 = fmaxf(m3, v.w); s3 = s3 * __expf(m3 - n3) + __expf(v.w - n3); m3 = n3;
  }
  long o = ((long)blockIdx.y * 8 + blockIdx.x) * 1024 + threadIdx.x * 4;
  *(float4*)&colMp[o] = make_float4(m0, m1, m2, m3);
  *(float4*)&colSp[o] = make_float4(s0, s1, s2, s3);
}

// ---------- phase 2: combine 8 chunk stats per column ----------
__global__ __launch_bounds__(256) void k_colcombine(const float* __restrict__ colMp,
                                                    const float* __restrict__ colSp,
                                                    float* __restrict__ colM,
                                                    float* __restrict__ colIS) {
  int idx = blockIdx.x * 256 + threadIdx.x;
  int b = idx >> 10, c = idx & 1023;
  float m = -3.4e38f;
  float mc[8], sc[8];
#pragma unroll
  for (int k = 0; k < 8; ++k) {
    mc[k] = colMp[((long)b * 8 + k) * 1024 + c];
    sc[k] = colSp[((long)b * 8 + k) * 1024 + c];
    m = fmaxf(m, mc[k]);
  }
  float s = 0.f;
#pragma unroll
  for (int k = 0; k < 8; ++k) s += sc[k] * __expf(mc[k] - m);
  colM[idx] = m;
  colIS[idx] = 1.0f / s;
}

// ---------- phase 3: fused row softmax -> P, column-softmax apply -> P2 ----------
__global__ __launch_bounds__(256) void k_softmax(const float* __restrict__ E,
                                                 unsigned short* __restrict__ P,
                                                 unsigned short* __restrict__ P2,
                                                 const float* __restrict__ colM,
                                                 const float* __restrict__ colIS) {
  long row = blockIdx.x;
  const float* e = E + row * 1024;
  int t = threadIdx.x;
  float4 v = *(const float4*)&e[t * 4];
  float m = fmaxf(fmaxf(v.x, v.y), fmaxf(v.z, v.w));
#pragma unroll
  for (int o = 32; o; o >>= 1) m = fmaxf(m, __shfl_xor(m, o));
  __shared__ float red[4];
  __shared__ float red2[4];
  int wid = t >> 6;
  if ((t & 63) == 0) red[wid] = m;
  __syncthreads();
  m = fmaxf(fmaxf(red[0], red[1]), fmaxf(red[2], red[3]));
  float p0 = __expf(v.x - m), p1 = __expf(v.y - m);
  float p2 = __expf(v.z - m), p3 = __expf(v.w - m);
  float s = p0 + p1 + p2 + p3;
#pragma unroll
  for (int o = 32; o; o >>= 1) s += __shfl_xor(s, o);
  if ((t & 63) == 0) red2[wid] = s;
  __syncthreads();
  s = red2[0] + red2[1] + red2[2] + red2[3];
  float inv = 1.0f / s;
  *(ushort4*)&P[row * 1024 + t * 4] =
      make_ushort4(f2bf(p0 * inv), f2bf(p1 * inv), f2bf(p2 * inv), f2bf(p3 * inv));
  long cb = (row >> 10) * 1024 + t * 4;
  float4 cm = *(const float4*)&colM[cb];
  float4 ci = *(const float4*)&colIS[cb];
  *(ushort4*)&P2[row * 1024 + t * 4] =
      make_ushort4(f2bf(__expf(v.x - cm.x) * ci.x), f2bf(__expf(v.y - cm.y) * ci.y),
                   f2bf(__expf(v.z - cm.z) * ci.z), f2bf(__expf(v.w - cm.w) * ci.w));
}

// ---------- 256x256 8-phase GEMM-BT (m201-style): C[m,n] = sum_k A[m,k]*Bt[n,k] ----------
// 512 threads = 8 waves (2M x 4N), wave tile 128x64, BK=64, 128KiB dbuf LDS,
// XOR chunk swizzle (src-side + read-side), per-phase half-tile staging,
// counted vmcnt(4) once per K-tile, raw s_barrier, setprio on MFMA clusters.
// Fragment reuse: af per m-half spans 2 phases, bn0 spans ph1+ph4, bn1 ph2+ph3
// -> 24 ds_read_b128 per wave per K-tile (the per-wave minimum).
// Staging safety: A of T(h+1) -> other buf (idle). B of T(h+2) -> current buf,
// issued ph3/ph4, after all B reads of this buf completed (ph2 barrier).
template <bool BIAS_RELU, bool OUT_BF16>
__global__ __launch_bounds__(512, 2) void k_gemm256(
    const unsigned short* __restrict__ A, long lda, long aBatch,
    const unsigned short* __restrict__ Bt, long ldb, long bBatch,
    void* __restrict__ C, long ldc, long cBatch,
    const float* __restrict__ bias, int K) {
  __shared__ unsigned short As[2][16384];  // [buf][256 rows x 64 cols]
  __shared__ unsigned short Bs[2][16384];
  const int t = threadIdx.x;
  const int l = t & 63;
  const int lr = l & 15, lh = l >> 4;
  const int w = t >> 6;
  const int wm = w >> 2, wn = w & 3;  // 2M x 4N waves

  // XCD-affinity remap (nwg % 8 == 0 guaranteed by launcher)
  const int gx = gridDim.x, gy = gridDim.y;
  const int nwg = gx * gy * gridDim.z;
  const int hw = blockIdx.x + gx * (blockIdx.y + gy * blockIdx.z);
  const int q = nwg >> 3;
  const int logical = (hw & 7) * q + (hw >> 3);
  const int bx = logical % gx;
  const int rem = logical / gx;
  const int by = rem % gy;
  const int bz = rem / gy;

  const long m0 = (long)by * 256;
  const long n0 = (long)bx * 256;
  const unsigned short* Ab = A + (long)bz * aBatch + m0 * lda;
  const unsigned short* Bb = Bt + (long)bz * bBatch + n0 * ldb;

  // staging one half-tile (128 rows x 64 cols) = 2 gl_lds/thread; LDS dest is
  // wave-uniform + lane*16 (verified: (l>>3)*128 + (l&7)*16 == l*16).
  const int tr8 = t >> 3;  // 0..63
  const int tc8 = t & 7;
  auto stage = [&](unsigned short* dst, const unsigned short* g, long ld,
                   int half, int k0) {
#pragma unroll
    for (int r = 0; r < 2; ++r) {
      const int lrow = half * 128 + r * 64 + tr8;
      const int sch = tc8 ^ (lrow & 7);  // src pre-swizzle
      gl_lds16(g + (long)lrow * ld + k0 + sch * 8, dst + lrow * 64 + tc8 * 8);
    }
  };

  f32x4 acc[8][4];
#pragma unroll
  for (int i = 0; i < 8; ++i)
#pragma unroll
    for (int j = 0; j < 4; ++j) acc[i][j] = (f32x4){0.f, 0.f, 0.f, 0.f};

  bf16x8 af[4][2], bn0[2][2], bn1[2][2];
  const int rk0 = ((0 * 4 + lh) ^ (lr & 7)) * 8;  // read chunk, kk=0
  const int rk1 = ((1 * 4 + lh) ^ (lr & 7)) * 8;  // read chunk, kk=1

  const int NT = K >> 6;  // NT >= 2 always (K >= 128)

  // ---- prologue: T0 fully + B of T1; leaves B(T1)=4 loads in flight ----
  stage(As[0], Ab, lda, 0, 0); stage(As[0], Ab, lda, 1, 0);
  stage(Bs[0], Bb, ldb, 0, 0); stage(Bs[0], Bb, ldb, 1, 0);
  stage(Bs[1], Bb, ldb, 0, 64); stage(Bs[1], Bb, ldb, 1, 64);
  asm volatile("s_waitcnt vmcnt(4)" ::: "memory");
  __builtin_amdgcn_s_barrier();

  for (int h = 0; h < NT; ++h) {
    const int b = h & 1;
    const unsigned short* Ac = As[b];
    const unsigned short* Bc = Bs[b];
    unsigned short* Anx = As[b ^ 1];
    unsigned short* Bcur = Bs[b];
    const int kA = (h + 1) << 6;
    const int kB = (h + 2) << 6;
    const bool stA = (h + 1 < NT);
    const bool stB = (h + 2 < NT);

    // ---- phase 1: read af(mh0) + bn0 ; stage A-h0 of T(h+1) ; MFMA (mh0,nh0)
#pragma unroll
    for (int mm = 0; mm < 4; ++mm) {
      const unsigned short* rp = &Ac[(wm * 128 + mm * 16 + lr) * 64];
      af[mm][0] = *(const bf16x8*)&rp[rk0];
      af[mm][1] = *(const bf16x8*)&rp[rk1];
    }
#pragma unroll
    for (int nn = 0; nn < 2; ++nn) {
      const unsigned short* rp = &Bc[(wn * 64 + nn * 16 + lr) * 64];
      bn0[nn][0] = *(const bf16x8*)&rp[rk0];
      bn0[nn][1] = *(const bf16x8*)&rp[rk1];
    }
    if (stA) stage(Anx, Ab, lda, 0, kA);
    __builtin_amdgcn_s_barrier();
    __builtin_amdgcn_s_setprio(1);
#pragma unroll
    for (int mm = 0; mm < 4; ++mm)
#pragma unroll
      for (int nn = 0; nn < 2; ++nn)
#pragma unroll
        for (int kk = 0; kk < 2; ++kk)
          acc[mm][nn] = __builtin_amdgcn_mfma_f32_16x16x32_bf16(
              af[mm][kk], bn0[nn][kk], acc[mm][nn], 0, 0, 0);
    __builtin_amdgcn_s_setprio(0);
    __builtin_amdgcn_s_barrier();

    // ---- phase 2: read bn1 ; stage A-h1 of T(h+1) ; MFMA (mh0,nh1)
#pragma unroll
    for (int nn = 0; nn < 2; ++nn) {
      const unsigned short* rp = &Bc[(wn * 64 + 32 + nn * 16 + lr) * 64];
      bn1[nn][0] = *(const bf16x8*)&rp[rk0];
      bn1[nn][1] = *(const bf16x8*)&rp[rk1];
    }
    if (stA) stage(Anx, Ab, lda, 1, kA);
    __builtin_amdgcn_s_barrier();
    __builtin_amdgcn_s_setprio(1);
#pragma unroll
    for (int mm = 0; mm < 4; ++mm)
#pragma unroll
      for (int nn = 0; nn < 2; ++nn)
#pragma unroll
        for (int kk = 0; kk < 2; ++kk)
          acc[mm][2 + nn] = __builtin_amdgcn_mfma_f32_16x16x32_bf16(
              af[mm][kk], bn1[nn][kk], acc[mm][2 + nn], 0, 0, 0);
    __builtin_amdgcn_s_setprio(0);
    __builtin_amdgcn_s_barrier();

    // ---- phase 3: read af(mh1) ; stage B-h0 of T(h+2) ; MFMA (mh1,nh1)
#pragma unroll
    for (int mm = 0; mm < 4; ++mm) {
      const unsigned short* rp = &Ac[(wm * 128 + 64 + mm * 16 + lr) * 64];
      af[mm][0] = *(const bf16x8*)&rp[rk0];
      af[mm][1] = *(const bf16x8*)&rp[rk1];
    }
    if (stB) stage(Bcur, Bb, ldb, 0, kB);
    __builtin_amdgcn_s_barrier();
    __builtin_amdgcn_s_setprio(1);
#pragma unroll
    for (int mm = 0; mm < 4; ++mm)
#pragma unroll
      for (int nn = 0; nn < 2; ++nn)
#pragma unroll
        for (int kk = 0; kk < 2; ++kk)
          acc[4 + mm][2 + nn] = __builtin_amdgcn_mfma_f32_16x16x32_bf16(
              af[mm][kk], bn1[nn][kk], acc[4 + mm][2 + nn], 0, 0, 0);
    __builtin_amdgcn_s_setprio(0);
    __builtin_amdgcn_s_barrier();

    // ---- phase 4: no ds_reads ; stage B-h1 of T(h+2) ; MFMA (mh1,nh0)
    if (stB) stage(Bcur, Bb, ldb, 1, kB);
    __builtin_amdgcn_s_barrier();
    __builtin_amdgcn_s_setprio(1);
#pragma unroll
    for (int mm = 0; mm < 4; ++mm)
#pragma unroll
      for (int nn = 0; nn < 2; ++nn)
#pragma unroll
        for (int kk = 0; kk < 2; ++kk)
          acc[4 + mm][nn] = __builtin_amdgcn_mfma_f32_16x16x32_bf16(
              af[mm][kk], bn0[nn][kk], acc[4 + mm][nn], 0, 0, 0);
    __builtin_amdgcn_s_setprio(0);
    // drain exactly T(h+1): leaves this group's B(T(h+2)) = 4 loads in flight
    if (stB) {
      asm volatile("s_waitcnt vmcnt(4)" ::: "memory");
    } else {
      asm volatile("s_waitcnt vmcnt(0)" ::: "memory");
    }
    __builtin_amdgcn_s_barrier();
  }

  // ---- epilogue: wave writes its 128x64 C block ----
  const long crow0 = m0 + wm * 128;
  const long ccol0 = n0 + wn * 64;
#pragma unroll
  for (int n = 0; n < 4; ++n) {
    const long col = ccol0 + n * 16 + lr;
    float bv = 0.f;
    if constexpr (BIAS_RELU) bv = bias[col];
#pragma unroll
    for (int m = 0; m < 8; ++m) {
#pragma unroll
      for (int r = 0; r < 4; ++r) {
        const long row = crow0 + m * 16 + lh * 4 + r;
        float x = acc[m][n][r];
        if constexpr (BIAS_RELU) x = fmaxf(x + bv, 0.f);
        if constexpr (OUT_BF16)
          ((unsigned short*)C)[(long)bz * cBatch + row * ldc + col] = f2bf(x);
        else
          ((float*)C)[(long)bz * cBatch + row * ldc + col] = x;
      }
    }
  }
}

// ---------- launcher ----------
extern "C" void kernel_launch(void* const* d_in, const int* in_sizes, int n_in,
                              void* d_out, int out_size, void* d_ws, size_t ws_size,
                              hipStream_t stream) {
  const float* A_in = (const float*)d_in[0];  // [32,1024,768]
  const float* B_in = (const float*)d_in[1];  // [32,1024,768]
  const float* W1 = (const float*)d_in[2];    // [768,1024]
  const float* b1 = (const float*)d_in[3];    // [1024]
  const float* W2 = (const float*)d_in[4];    // [1024,1024]
  const float* b2 = (const float*)d_in[5];    // [1024]

  char* ws = (char*)d_ws;
  unsigned short* Xbf  = (unsigned short*)(ws + 0L);           // 65536x768 bf16 (96MB); later P
  unsigned short* H    = (unsigned short*)(ws + 100663296L);   // 65536x1024 bf16 (128MB); later stats
  unsigned short* F    = (unsigned short*)(ws + 234881024L);   // 65536x1024 bf16 (128MB); later P2
  unsigned short* BinT = (unsigned short*)(ws + 369098752L);   // 32x768x1024 bf16 (48MB)
  unsigned short* W1T  = (unsigned short*)(ws + 419430400L);   // 1024x768 bf16
  unsigned short* W2T  = (unsigned short*)(ws + 421003264L);   // 1024x1024 bf16
  unsigned short* P    = (unsigned short*)(ws + 0L);           // 32x1024x1024 bf16 (64MB)
  unsigned short* P2   = (unsigned short*)(ws + 234881024L);   // 32x1024x1024 bf16 (64MB)
  float* colMp = (float*)(ws + 100663296L);
  float* colSp = (float*)(ws + 100663296L + 1048576L);
  float* colM  = (float*)(ws + 100663296L + 2097152L);
  float* colIS = (float*)(ws + 100663296L + 2228224L);
  float* E  = (float*)d_out;                                   // 32x1024x1024 f32 (134MB)
  float* beta = (float*)d_out;
  float* alpha = (float*)d_out + 25165824L;

  // 1) converts / transposes of inputs
  k_convert<<<12288, 256, 0, stream>>>(A_in, Xbf, 3145728);
  k_convert<<<12288, 256, 0, stream>>>(B_in, Xbf + 25165824L, 3145728);
  k_transpose<unsigned short><<<dim3(16, 12, 1), 256, 0, stream>>>(W1, W1T, 768, 1024, 0, 0);
  k_transpose<unsigned short><<<dim3(16, 16, 1), 256, 0, stream>>>(W2, W2T, 1024, 1024, 0, 0);
  k_transpose<unsigned short><<<dim3(12, 16, 32), 256, 0, stream>>>(B_in, BinT, 1024, 768, 786432L, 786432L);

  // 2) MLP: H = relu(X@W1+b1); F = relu(H@W2+b2)
  k_gemm256<true, true><<<dim3(4, 256, 1), 512, 0, stream>>>(
      Xbf, 768, 0, W1T, 768, 0, (void*)H, 1024, 0, b1, 768);
  k_gemm256<true, true><<<dim3(4, 256, 1), 512, 0, stream>>>(
      H, 1024, 0, W2T, 1024, 0, (void*)F, 1024, 0, b2, 1024);

  // 3) E[b] = fA[b] @ fB[b]^T
  k_gemm256<false, false><<<dim3(4, 4, 32), 512, 0, stream>>>(
      F, 1024, 1048576L, F + 33554432L, 1024, 1048576L, (void*)E, 1024, 1048576L, nullptr, 1024);

  // 4) column stats, combine, fused row-softmax + col-apply
  k_colstats<<<dim3(8, 32), 256, 0, stream>>>(E, colMp, colSp);
  k_colcombine<<<128, 256, 0, stream>>>(colMp, colSp, colM, colIS);
  k_softmax<<<32768, 256, 0, stream>>>(E, P, P2, colM, colIS);

  // 5) beta = P @ B ; alpha = P2 @ B
  k_gemm256<false, false><<<dim3(3, 4, 32), 512, 0, stream>>>(
      P, 1024, 1048576L, BinT, 1024, 786432L, (void*)beta, 768, 786432L, nullptr, 1024);
  k_gemm256<false, false><<<dim3(3, 4, 32), 512, 0, stream>>>(
      P2, 1024, 1048576L, BinT, 1024, 786432L, (void*)alpha, 768, 786432L, nullptr, 1024);
}

// Round 8
// 712.526 us; speedup vs baseline: 1.0815x; 1.0815x over previous
//
#include <hip/hip_runtime.h>
#include <hip/hip_bf16.h>

// ---------- types ----------
typedef __attribute__((ext_vector_type(8))) short bf16x8;  // 8 bf16 in 4 VGPRs
typedef __attribute__((ext_vector_type(4))) float f32x4;

__device__ __forceinline__ unsigned short f2bf(float f) {
  union { float f; unsigned u; } v; v.f = f;
  unsigned r = v.u + 0x7FFFu + ((v.u >> 16) & 1u);  // RNE
  return (unsigned short)(r >> 16);
}

__device__ __forceinline__ void gl_lds16(const void* g, void* l) {
  __builtin_amdgcn_global_load_lds(
      (__attribute__((address_space(1))) void*)(g),
      (__attribute__((address_space(3))) void*)(l), 16, 0, 0);
}

// ---------- f32 -> bf16 convert (vectorized) ----------
__global__ __launch_bounds__(256) void k_convert(const float* __restrict__ in,
                                                 unsigned short* __restrict__ out,
                                                 int n8) {
  int i = blockIdx.x * 256 + threadIdx.x;
  if (i >= n8) return;
  const float4* ip = (const float4*)in;
  float4 v0 = ip[2 * i], v1 = ip[2 * i + 1];
  ushort4 o0 = make_ushort4(f2bf(v0.x), f2bf(v0.y), f2bf(v0.z), f2bf(v0.w));
  ushort4 o1 = make_ushort4(f2bf(v1.x), f2bf(v1.y), f2bf(v1.z), f2bf(v1.w));
  ((ushort4*)out)[2 * i] = o0;
  ((ushort4*)out)[2 * i + 1] = o1;
}

// ---------- batched transpose: in [R][C] f32 -> out [C][R] (f32 or bf16) ----------
template <typename OutT>
__global__ __launch_bounds__(256) void k_transpose(const float* __restrict__ in,
                                                   OutT* __restrict__ out,
                                                   int R, int C,
                                                   long inStride, long outStride) {
  __shared__ float tile[64][65];
  const float* ib = in + (long)blockIdx.z * inStride;
  OutT* ob = out + (long)blockIdx.z * outStride;
  int tc = blockIdx.x * 64;
  int tr = blockIdx.y * 64;
  int t = threadIdx.x;
  int lr = t >> 4;
  int lc = (t & 15) * 4;
#pragma unroll
  for (int rr = 0; rr < 64; rr += 16) {
    float4 v = *(const float4*)&ib[(long)(tr + rr + lr) * C + tc + lc];
    tile[rr + lr][lc + 0] = v.x;
    tile[rr + lr][lc + 1] = v.y;
    tile[rr + lr][lc + 2] = v.z;
    tile[rr + lr][lc + 3] = v.w;
  }
  __syncthreads();
#pragma unroll
  for (int ii = 0; ii < 64; ii += 16) {
    int i = ii + lr;
    if constexpr (sizeof(OutT) == 2) {
      ushort4 w = make_ushort4(f2bf(tile[lc + 0][i]), f2bf(tile[lc + 1][i]),
                               f2bf(tile[lc + 2][i]), f2bf(tile[lc + 3][i]));
      *(ushort4*)&ob[(long)(tc + i) * R + tr + lc] = w;
    } else {
      float4 w = make_float4(tile[lc + 0][i], tile[lc + 1][i],
                             tile[lc + 2][i], tile[lc + 3][i]);
      *(float4*)&ob[(long)(tc + i) * R + tr + lc] = w;
    }
  }
}

// ---------- phase 1: partial column stats (online max/sumexp over 128-row chunk) ----------
__global__ __launch_bounds__(256) void k_colstats(const float* __restrict__ E,
                                                  float* __restrict__ colMp,
                                                  float* __restrict__ colSp) {
  const float* e = E + (long)blockIdx.y * 1048576L + (long)blockIdx.x * 131072L +
                   threadIdx.x * 4;
  float m0 = -3.4e38f, m1 = -3.4e38f, m2 = -3.4e38f, m3 = -3.4e38f;
  float s0 = 0.f, s1 = 0.f, s2 = 0.f, s3 = 0.f;
  for (int r = 0; r < 128; ++r) {
    float4 v = *(const float4*)(e + (long)r * 1024);
    float n0 = fmaxf(m0, v.x); s0 = s0 * __expf(m0 - n0) + __expf(v.x - n0); m0 = n0;
    float n1 = fmaxf(m1, v.y); s1 = s1 * __expf(m1 - n1) + __expf(v.y - n1); m1 = n1;
    float n2 = fmaxf(m2, v.z); s2 = s2 * __expf(m2 - n2) + __expf(v.z - n2); m2 = n2;
    float n3 = fmaxf(m3, v.w); s3 = s3 * __expf(m3 - n3) + __expf(v.w - n3); m3 = n3;
  }
  long o = ((long)blockIdx.y * 8 + blockIdx.x) * 1024 + threadIdx.x * 4;
  *(float4*)&colMp[o] = make_float4(m0, m1, m2, m3);
  *(float4*)&colSp[o] = make_float4(s0, s1, s2, s3);
}

// ---------- phase 2: combine 8 chunk stats per column ----------
__global__ __launch_bounds__(256) void k_colcombine(const float* __restrict__ colMp,
                                                    const float* __restrict__ colSp,
                                                    float* __restrict__ colM,
                                                    float* __restrict__ colIS) {
  int idx = blockIdx.x * 256 + threadIdx.x;
  int b = idx >> 10, c = idx & 1023;
  float m = -3.4e38f;
  float mc[8], sc[8];
#pragma unroll
  for (int k = 0; k < 8; ++k) {
    mc[k] = colMp[((long)b * 8 + k) * 1024 + c];
    sc[k] = colSp[((long)b * 8 + k) * 1024 + c];
    m = fmaxf(m, mc[k]);
  }
  float s = 0.f;
#pragma unroll
  for (int k = 0; k < 8; ++k) s += sc[k] * __expf(mc[k] - m);
  colM[idx] = m;
  colIS[idx] = 1.0f / s;
}

// ---------- phase 3: fused row softmax -> P, column-softmax apply -> P2 ----------
__global__ __launch_bounds__(256) void k_softmax(const float* __restrict__ E,
                                                 unsigned short* __restrict__ P,
                                                 unsigned short* __restrict__ P2,
                                                 const float* __restrict__ colM,
                                                 const float* __restrict__ colIS) {
  long row = blockIdx.x;
  const float* e = E + row * 1024;
  int t = threadIdx.x;
  float4 v = *(const float4*)&e[t * 4];
  float m = fmaxf(fmaxf(v.x, v.y), fmaxf(v.z, v.w));
#pragma unroll
  for (int o = 32; o; o >>= 1) m = fmaxf(m, __shfl_xor(m, o));
  __shared__ float red[4];
  __shared__ float red2[4];
  int wid = t >> 6;
  if ((t & 63) == 0) red[wid] = m;
  __syncthreads();
  m = fmaxf(fmaxf(red[0], red[1]), fmaxf(red[2], red[3]));
  float p0 = __expf(v.x - m), p1 = __expf(v.y - m);
  float p2 = __expf(v.z - m), p3 = __expf(v.w - m);
  float s = p0 + p1 + p2 + p3;
#pragma unroll
  for (int o = 32; o; o >>= 1) s += __shfl_xor(s, o);
  if ((t & 63) == 0) red2[wid] = s;
  __syncthreads();
  s = red2[0] + red2[1] + red2[2] + red2[3];
  float inv = 1.0f / s;
  *(ushort4*)&P[row * 1024 + t * 4] =
      make_ushort4(f2bf(p0 * inv), f2bf(p1 * inv), f2bf(p2 * inv), f2bf(p3 * inv));
  long cb = (row >> 10) * 1024 + t * 4;
  float4 cm = *(const float4*)&colM[cb];
  float4 ci = *(const float4*)&colIS[cb];
  *(ushort4*)&P2[row * 1024 + t * 4] =
      make_ushort4(f2bf(__expf(v.x - cm.x) * ci.x), f2bf(__expf(v.y - cm.y) * ci.y),
                   f2bf(__expf(v.z - cm.z) * ci.z), f2bf(__expf(v.w - cm.w) * ci.w));
}

// ---------- GEMM-BT: C[m,n] = sum_k A[m,k] * Bt[n,k]  (both bf16, K-contiguous) ----------
// Block tile 128M x 256N, BK=64, 256 threads = 4 waves (2x2), wave tile 64x128.
// Fatter wave tile cuts LDS-read bytes/MFMA 512->375 B (LDS-traffic model:
// per-CU K-tile bytes = 8 waves*24KB read + 96KB stage-write = 288KB -> 1125cy
// @256B/cyc vs 620cy MFMA -> cap ~55%). Multi-block/CU (2) keeps cross-block
// LDS/MFMA overlap that the 1-block 256^2 variants lost (rounds 5/7 lesson).
// XCD-affinity remap + both-sides XOR chunk swizzle, same as round 6.
template <bool BIAS_RELU, bool OUT_BF16>
__global__ __launch_bounds__(256, 2) void k_gemm_bt(
    const unsigned short* __restrict__ A, long lda, long aBatch,
    const unsigned short* __restrict__ Bt, long ldb, long bBatch,
    void* __restrict__ C, long ldc, long cBatch,
    const float* __restrict__ bias, int K) {
  __shared__ unsigned short As[128 * 64];  // M x BK
  __shared__ unsigned short Bs[256 * 64];  // N x BK
  const int t = threadIdx.x;
  const int w = t >> 6, l = t & 63;
  const int lr = l & 15, lh = l >> 4;
  const int wm = w >> 1, wn = w & 1;  // wave tile 64M x 128N

  // XCD-affinity remap (grid size % 8 == 0 guaranteed by launcher)
  const int gx = gridDim.x, gy = gridDim.y;
  const int nwg = gx * gy * gridDim.z;
  const int hw = blockIdx.x + gx * (blockIdx.y + gy * blockIdx.z);
  const int q = nwg >> 3;
  const int logical = (hw & 7) * q + (hw >> 3);
  const int bx = logical % gx;
  const int rem = logical / gx;
  const int by = rem % gy;
  const int bz = rem / gy;

  const long m0 = (long)by * 128;
  const long n0 = (long)bx * 256;
  const unsigned short* Ab = A + (long)bz * aBatch;
  const unsigned short* Bb = Bt + (long)bz * bBatch;

  // staging: A = 128 rows (4 rounds), B = 256 rows (8 rounds); 256 threads,
  // each round covers 32 rows x 64 cols. dest = wave-uniform + lane*16 (ok).
  // source chunk pre-swizzled: LDS[row][c] = global[row][c ^ (row&7)].
  const int srow = t >> 3;                       // 0..31
  const int sc16 = (t & 7) ^ (srow & 7);         // swizzled 16B-chunk
  const int scol = sc16 * 8;                     // in shorts
  const unsigned short* ag = Ab + (m0 + srow) * lda + scol;
  const unsigned short* bg = Bb + (n0 + srow) * ldb + scol;
  unsigned short* al = &As[srow * 64 + (t & 7) * 8];
  unsigned short* bl = &Bs[srow * 64 + (t & 7) * 8];

  f32x4 acc[4][8];
#pragma unroll
  for (int i = 0; i < 4; ++i)
#pragma unroll
    for (int j = 0; j < 8; ++j) acc[i][j] = (f32x4){0.f, 0.f, 0.f, 0.f};

  for (int k0 = 0; k0 < K; k0 += 64) {
#pragma unroll
    for (int j = 0; j < 4; ++j)
      gl_lds16(ag + (long)(j * 32) * lda + k0, al + j * 2048);
#pragma unroll
    for (int j = 0; j < 8; ++j)
      gl_lds16(bg + (long)(j * 32) * ldb + k0, bl + j * 2048);
    __syncthreads();
#pragma unroll
    for (int kk = 0; kk < 2; ++kk) {
      const int rsw = ((kk * 4 + lh) ^ (lr & 7)) * 8;  // read-side swizzled chunk
      bf16x8 af[4], bfr[8];
#pragma unroll
      for (int m = 0; m < 4; ++m)
        af[m] = *(const bf16x8*)&As[(wm * 64 + m * 16 + lr) * 64 + rsw];
#pragma unroll
      for (int n = 0; n < 8; ++n)
        bfr[n] = *(const bf16x8*)&Bs[(wn * 128 + n * 16 + lr) * 64 + rsw];
#pragma unroll
      for (int m = 0; m < 4; ++m)
#pragma unroll
        for (int n = 0; n < 8; ++n)
          acc[m][n] = __builtin_amdgcn_mfma_f32_16x16x32_bf16(af[m], bfr[n], acc[m][n], 0, 0, 0);
    }
    __syncthreads();
  }

  const long crow = m0 + wm * 64;
  const long ccol = n0 + wn * 128;
#pragma unroll
  for (int n = 0; n < 8; ++n) {
    const long col = ccol + n * 16 + lr;
    float bv = 0.f;
    if constexpr (BIAS_RELU) bv = bias[col];
#pragma unroll
    for (int m = 0; m < 4; ++m) {
      f32x4 v = acc[m][n];
#pragma unroll
      for (int r = 0; r < 4; ++r) {
        const long rrow = crow + m * 16 + lh * 4 + r;
        float x = v[r];
        if constexpr (BIAS_RELU) x = fmaxf(x + bv, 0.f);
        if constexpr (OUT_BF16)
          ((unsigned short*)C)[(long)bz * cBatch + rrow * ldc + col] = f2bf(x);
        else
          ((float*)C)[(long)bz * cBatch + rrow * ldc + col] = x;
      }
    }
  }
}

// ---------- launcher ----------
extern "C" void kernel_launch(void* const* d_in, const int* in_sizes, int n_in,
                              void* d_out, int out_size, void* d_ws, size_t ws_size,
                              hipStream_t stream) {
  const float* A_in = (const float*)d_in[0];  // [32,1024,768]
  const float* B_in = (const float*)d_in[1];  // [32,1024,768]
  const float* W1 = (const float*)d_in[2];    // [768,1024]
  const float* b1 = (const float*)d_in[3];    // [1024]
  const float* W2 = (const float*)d_in[4];    // [1024,1024]
  const float* b2 = (const float*)d_in[5];    // [1024]

  char* ws = (char*)d_ws;
  unsigned short* Xbf  = (unsigned short*)(ws + 0L);           // 65536x768 bf16 (96MB); later P
  unsigned short* H    = (unsigned short*)(ws + 100663296L);   // 65536x1024 bf16 (128MB); later stats
  unsigned short* F    = (unsigned short*)(ws + 234881024L);   // 65536x1024 bf16 (128MB); later P2
  unsigned short* BinT = (unsigned short*)(ws + 369098752L);   // 32x768x1024 bf16 (48MB)
  unsigned short* W1T  = (unsigned short*)(ws + 419430400L);   // 1024x768 bf16
  unsigned short* W2T  = (unsigned short*)(ws + 421003264L);   // 1024x1024 bf16
  unsigned short* P    = (unsigned short*)(ws + 0L);           // 32x1024x1024 bf16 (64MB)
  unsigned short* P2   = (unsigned short*)(ws + 234881024L);   // 32x1024x1024 bf16 (64MB)
  float* colMp = (float*)(ws + 100663296L);
  float* colSp = (float*)(ws + 100663296L + 1048576L);
  float* colM  = (float*)(ws + 100663296L + 2097152L);
  float* colIS = (float*)(ws + 100663296L + 2228224L);
  float* E  = (float*)d_out;                                   // 32x1024x1024 f32 (134MB)
  float* beta = (float*)d_out;
  float* alpha = (float*)d_out + 25165824L;

  // 1) converts / transposes of inputs
  k_convert<<<12288, 256, 0, stream>>>(A_in, Xbf, 3145728);
  k_convert<<<12288, 256, 0, stream>>>(B_in, Xbf + 25165824L, 3145728);
  k_transpose<unsigned short><<<dim3(16, 12, 1), 256, 0, stream>>>(W1, W1T, 768, 1024, 0, 0);
  k_transpose<unsigned short><<<dim3(16, 16, 1), 256, 0, stream>>>(W2, W2T, 1024, 1024, 0, 0);
  k_transpose<unsigned short><<<dim3(12, 16, 32), 256, 0, stream>>>(B_in, BinT, 1024, 768, 786432L, 786432L);

  // 2) MLP: H = relu(X@W1+b1); F = relu(H@W2+b2)
  k_gemm_bt<true, true><<<dim3(4, 512, 1), 256, 0, stream>>>(
      Xbf, 768, 0, W1T, 768, 0, (void*)H, 1024, 0, b1, 768);
  k_gemm_bt<true, true><<<dim3(4, 512, 1), 256, 0, stream>>>(
      H, 1024, 0, W2T, 1024, 0, (void*)F, 1024, 0, b2, 1024);

  // 3) E[b] = fA[b] @ fB[b]^T
  k_gemm_bt<false, false><<<dim3(4, 8, 32), 256, 0, stream>>>(
      F, 1024, 1048576L, F + 33554432L, 1024, 1048576L, (void*)E, 1024, 1048576L, nullptr, 1024);

  // 4) column stats, combine, fused row-softmax + col-apply
  k_colstats<<<dim3(8, 32), 256, 0, stream>>>(E, colMp, colSp);
  k_colcombine<<<128, 256, 0, stream>>>(colMp, colSp, colM, colIS);
  k_softmax<<<32768, 256, 0, stream>>>(E, P, P2, colM, colIS);

  // 5) beta = P @ B ; alpha = P2 @ B
  k_gemm_bt<false, false><<<dim3(3, 8, 32), 256, 0, stream>>>(
      P, 1024, 1048576L, BinT, 1024, 786432L, (void*)beta, 768, 786432L, nullptr, 1024);
  k_gemm_bt<false, false><<<dim3(3, 8, 32), 256, 0, stream>>>(
      P2, 1024, 1048576L, BinT, 1024, 786432L, (void*)alpha, 768, 786432L, nullptr, 1024);
}